// Round 12
// baseline (18.373 us; speedup 1.0000x reference)
//
#include <hip/hip_runtime.h>

#define TILE 64    // tile side handled by ONE wave, j per-lane
#define WPB  8     // waves (= tiles) per 512-thread block

__global__ __launch_bounds__(512) void cindex_pairs_kernel(
    const float* __restrict__ risk,
    const float* __restrict__ tim,
    const int*   __restrict__ evt,
    uint4* __restrict__ part,          // per-block packed {conc, tie, comp, 0}
    int n, int ntile)
{
    const int tid  = threadIdx.x;
    const int wid  = tid >> 6;
    const int lane = tid & 63;
    const int t = blockIdx.x * WPB + wid;   // this wave's tile id

    __shared__ float2 s_pack[WPB][TILE];    // per-wave compacted (t_i, r_i)
    __shared__ int    s_idx[WPB][TILE];     // per-wave compacted lane (diag check)
    __shared__ unsigned int s_part[WPB][3];

    unsigned int nComp = 0, nConc = 0, nTie = 0;
    int cnt = 0;
    int i0 = 0, j0 = 0;
    bool diag = false;
    const bool active = (t < ntile);

    if (active) {
        // Decode lower-triangle pair (p >= q): p*(p+1)/2 <= t < (p+1)*(p+2)/2
        int p = (int)((sqrtf(8.0f * (float)t + 1.0f) - 1.0f) * 0.5f);
        while ((p + 1) * (p + 2) / 2 <= t) ++p;
        while (p * (p + 1) / 2 > t) --p;
        const int q = t - p * (p + 1) / 2;
        i0 = q * TILE;
        j0 = p * TILE;
        diag = (p == q);

        // ---- Stage: compact this wave's event-i's into its LDS segment ----
        int i = i0 + lane;
        bool inb = (i < n);
        float tv = inb ? tim[i]  : 0.0f;
        float rv = inb ? risk[i] : 0.0f;
        bool ev = inb && (evt[i] == 1);
        unsigned long long m = __ballot(ev);
        cnt = (int)__popcll(m);                        // wave-uniform
        int pos = (int)__popcll(m & ((1ull << lane) - 1ull));
        if (ev) { s_pack[wid][pos] = make_float2(tv, rv); s_idx[wid][pos] = lane; }
    }
    __syncthreads();   // orders staging ds_writes before loop ds_reads
    cnt = __builtin_amdgcn_readfirstlane(cnt);

    if (active) {
        // ---- Per-lane j data, register-resident ----
        const int j  = j0 + lane;
        const bool jv = (j < n);
        const float tj = jv ? tim[j]  : 0.0f;
        const float rj = jv ? risk[j] : 0.0f;
        const int  ejv = jv ? evt[j]  : -1;
        const bool ej1 = (ejv == 1);
        const bool ej0 = (ejv == 0);

        if (!diag) {
            // Off-diagonal: every staged i < every j (j0 >= i0+TILE).
            #pragma unroll 4
            for (int k = 0; k < cnt; ++k) {
                float2 tr = s_pack[wid][k];      // broadcast ds_read_b64
                float ti = tr.x, ri = tr.y;
                bool lt  = ti < tj;
                bool gt  = ti > tj;
                bool rgt = ri > rj;
                bool rlt = ri < rj;
                bool req = ri == rj;
                bool comp = ej1 | (ej0 & lt);
                bool conc = (ej1 & ((lt & rgt) | (gt & rlt))) | (ej0 & lt & rgt);
                nComp += (unsigned int)comp;
                nConc += (unsigned int)conc;
                nTie  += (unsigned int)(comp & req);
            }
        } else {
            // Diagonal tile: j0 == i0, enforce j > i  <=>  lane > staged lane.
            #pragma unroll 4
            for (int k = 0; k < cnt; ++k) {
                float2 tr = s_pack[wid][k];
                int   ii  = s_idx[wid][k];
                float ti = tr.x, ri = tr.y;
                bool ok  = lane > ii;
                bool lt  = ti < tj;
                bool gt  = ti > tj;
                bool rgt = ri > rj;
                bool rlt = ri < rj;
                bool req = ri == rj;
                bool comp = (ej1 | (ej0 & lt)) & ok;
                bool conc = ((ej1 & ((lt & rgt) | (gt & rlt))) | (ej0 & lt & rgt)) & ok;
                nComp += (unsigned int)comp;
                nConc += (unsigned int)conc;
                nTie  += (unsigned int)(comp & req);
            }
        }
    }

    // ---- Wave shuffle reduction -> per-wave LDS partial ----
    for (int off = 32; off > 0; off >>= 1) {
        nComp += __shfl_down(nComp, off, 64);
        nConc += __shfl_down(nConc, off, 64);
        nTie  += __shfl_down(nTie,  off, 64);
    }
    if (lane == 0) {
        s_part[wid][0] = nConc;
        s_part[wid][1] = nTie;
        s_part[wid][2] = nComp;
    }
    __syncthreads();
    if (tid == 0) {
        unsigned int c0 = 0, c1 = 0, c2 = 0;
        #pragma unroll
        for (int w = 0; w < WPB; ++w) {
            c0 += s_part[w][0];
            c1 += s_part[w][1];
            c2 += s_part[w][2];
        }
        part[blockIdx.x] = make_uint4(c0, c1, c2, 0u);   // one dwordx4 store
    }
}

__global__ __launch_bounds__(1024) void cindex_reduce_kernel(
    const uint4* __restrict__ part,
    float* __restrict__ out, int nslot)
{
    const int tid = threadIdx.x;
    unsigned int c0 = 0, c1 = 0, c2 = 0;
    for (int i = tid; i < nslot; i += 1024) {
        uint4 v = part[i];                               // one dwordx4 load
        c0 += v.x; c1 += v.y; c2 += v.z;
    }
    for (int off = 32; off > 0; off >>= 1) {
        c0 += __shfl_down(c0, off, 64);
        c1 += __shfl_down(c1, off, 64);
        c2 += __shfl_down(c2, off, 64);
    }
    __shared__ unsigned int s_part[16][3];
    const int wid  = tid >> 6;
    const int lane = tid & 63;
    if (lane == 0) {
        s_part[wid][0] = c0;
        s_part[wid][1] = c1;
        s_part[wid][2] = c2;
    }
    __syncthreads();
    if (tid == 0) {
        unsigned int t0 = 0, t1 = 0, t2 = 0;
        #pragma unroll
        for (int w = 0; w < 16; ++w) {
            t0 += s_part[w][0];
            t1 += s_part[w][1];
            t2 += s_part[w][2];
        }
        double conc = (double)t0;
        double tie  = (double)t1;
        double comp = (double)t2;
        float c;
        if (comp > 0.0) {
            c = (float)((conc + 0.5 * tie) / comp);
        } else {
            c = 0.5f;
        }
        out[0] = 1.0f - c;
    }
}

extern "C" void kernel_launch(void* const* d_in, const int* in_sizes, int n_in,
                              void* d_out, int out_size, void* d_ws, size_t ws_size,
                              hipStream_t stream)
{
    const float* risk = (const float*)d_in[0];   // (B,1) f32, flat B
    const float* tim  = (const float*)d_in[1];   // (B,)  f32
    const int*   evt  = (const int*)d_in[2];     // (B,)  i32
    float* out = (float*)d_out;
    uint4* part = (uint4*)d_ws;

    const int n = in_sizes[1];
    const int nt = (n + TILE - 1) / TILE;        // tile rows (128 for n=8192)
    const int ntile = nt * (nt + 1) / 2;         // triangular tile count (8256)
    const int nslot = (ntile + WPB - 1) / WPB;   // blocks / packed slots (1032)

    cindex_pairs_kernel<<<dim3(nslot), 512, 0, stream>>>(risk, tim, evt, part,
                                                         n, ntile);
    cindex_reduce_kernel<<<1, 1024, 0, stream>>>(part, out, nslot);
}

// Round 13
// 17.191 us; speedup vs baseline: 1.0687x; 1.0687x over previous
//
#include <hip/hip_runtime.h>

#define TILE 64    // tile side handled by ONE wave, j per-lane
#define WPB  4     // waves (= tiles) per 256-thread block (R11 optimum)

__global__ __launch_bounds__(256) void cindex_pairs_kernel(
    const float* __restrict__ risk,
    const float* __restrict__ tim,
    const int*   __restrict__ evt,
    uint4* __restrict__ part,          // per-block packed {conc, tie, comp, 0}
    int n, int ntile)
{
    const int tid  = threadIdx.x;
    const int wid  = tid >> 6;
    const int lane = tid & 63;
    const int t = blockIdx.x * WPB + wid;   // this wave's tile id

    __shared__ float2 s_pack[WPB][TILE];    // per-wave compacted (t_i, r_i)
    __shared__ int    s_idx[WPB][TILE];     // per-wave compacted lane (diag check)
    __shared__ unsigned int s_part[WPB][3];

    unsigned int nComp = 0, nConc = 0, nTie = 0;
    int cnt = 0;
    int i0 = 0, j0 = 0;
    bool diag = false;
    const bool active = (t < ntile);

    if (active) {
        // Decode lower-triangle pair (p >= q): p*(p+1)/2 <= t < (p+1)*(p+2)/2
        int p = (int)((sqrtf(8.0f * (float)t + 1.0f) - 1.0f) * 0.5f);
        while ((p + 1) * (p + 2) / 2 <= t) ++p;
        while (p * (p + 1) / 2 > t) --p;
        const int q = t - p * (p + 1) / 2;
        i0 = q * TILE;
        j0 = p * TILE;
        diag = (p == q);

        // ---- Stage: compact this wave's event-i's into its LDS segment ----
        int i = i0 + lane;
        bool inb = (i < n);
        float tv = inb ? tim[i]  : 0.0f;
        float rv = inb ? risk[i] : 0.0f;
        bool ev = inb && (evt[i] == 1);
        unsigned long long m = __ballot(ev);
        cnt = (int)__popcll(m);                        // wave-uniform
        int pos = (int)__popcll(m & ((1ull << lane) - 1ull));
        if (ev) { s_pack[wid][pos] = make_float2(tv, rv); s_idx[wid][pos] = lane; }
    }
    __syncthreads();   // orders staging ds_writes before loop ds_reads
    cnt = __builtin_amdgcn_readfirstlane(cnt);

    if (active) {
        // ---- Per-lane j data, register-resident ----
        const int j  = j0 + lane;
        const bool jv = (j < n);
        const float tj = jv ? tim[j]  : 0.0f;
        const float rj = jv ? risk[j] : 0.0f;
        const int  ejv = jv ? evt[j]  : -1;
        const bool ej1 = (ejv == 1);
        const bool ej0 = (ejv == 0);

        if (!diag) {
            // Off-diagonal: every staged i < every j (j0 >= i0+TILE).
            #pragma unroll 4
            for (int k = 0; k < cnt; ++k) {
                float2 tr = s_pack[wid][k];      // broadcast ds_read_b64
                float ti = tr.x, ri = tr.y;
                bool lt  = ti < tj;
                bool gt  = ti > tj;
                bool rgt = ri > rj;
                bool rlt = ri < rj;
                bool req = ri == rj;
                bool comp = ej1 | (ej0 & lt);
                bool conc = (ej1 & ((lt & rgt) | (gt & rlt))) | (ej0 & lt & rgt);
                nComp += (unsigned int)comp;
                nConc += (unsigned int)conc;
                nTie  += (unsigned int)(comp & req);
            }
        } else {
            // Diagonal tile: j0 == i0, enforce j > i  <=>  lane > staged lane.
            #pragma unroll 4
            for (int k = 0; k < cnt; ++k) {
                float2 tr = s_pack[wid][k];
                int   ii  = s_idx[wid][k];
                float ti = tr.x, ri = tr.y;
                bool ok  = lane > ii;
                bool lt  = ti < tj;
                bool gt  = ti > tj;
                bool rgt = ri > rj;
                bool rlt = ri < rj;
                bool req = ri == rj;
                bool comp = (ej1 | (ej0 & lt)) & ok;
                bool conc = ((ej1 & ((lt & rgt) | (gt & rlt))) | (ej0 & lt & rgt)) & ok;
                nComp += (unsigned int)comp;
                nConc += (unsigned int)conc;
                nTie  += (unsigned int)(comp & req);
            }
        }
    }

    // ---- Wave shuffle reduction -> per-wave LDS partial ----
    for (int off = 32; off > 0; off >>= 1) {
        nComp += __shfl_down(nComp, off, 64);
        nConc += __shfl_down(nConc, off, 64);
        nTie  += __shfl_down(nTie,  off, 64);
    }
    if (lane == 0) {
        s_part[wid][0] = nConc;
        s_part[wid][1] = nTie;
        s_part[wid][2] = nComp;
    }
    __syncthreads();
    if (tid == 0) {
        unsigned int c0 = 0, c1 = 0, c2 = 0;
        #pragma unroll
        for (int w = 0; w < WPB; ++w) {
            c0 += s_part[w][0];
            c1 += s_part[w][1];
            c2 += s_part[w][2];
        }
        part[blockIdx.x] = make_uint4(c0, c1, c2, 0u);   // one dwordx4 store
    }
}

__global__ __launch_bounds__(1024) void cindex_reduce_kernel(
    const uint4* __restrict__ part,
    float* __restrict__ out, int nslot)
{
    const int tid = threadIdx.x;
    unsigned int c0 = 0, c1 = 0, c2 = 0;
    for (int i = tid; i < nslot; i += 1024) {
        uint4 v = part[i];                               // one dwordx4 load
        c0 += v.x; c1 += v.y; c2 += v.z;
    }
    for (int off = 32; off > 0; off >>= 1) {
        c0 += __shfl_down(c0, off, 64);
        c1 += __shfl_down(c1, off, 64);
        c2 += __shfl_down(c2, off, 64);
    }
    __shared__ unsigned int s_part[16][3];
    const int wid  = tid >> 6;
    const int lane = tid & 63;
    if (lane == 0) {
        s_part[wid][0] = c0;
        s_part[wid][1] = c1;
        s_part[wid][2] = c2;
    }
    __syncthreads();
    if (tid == 0) {
        unsigned int t0 = 0, t1 = 0, t2 = 0;
        #pragma unroll
        for (int w = 0; w < 16; ++w) {
            t0 += s_part[w][0];
            t1 += s_part[w][1];
            t2 += s_part[w][2];
        }
        double conc = (double)t0;
        double tie  = (double)t1;
        double comp = (double)t2;
        float c;
        if (comp > 0.0) {
            c = (float)((conc + 0.5 * tie) / comp);
        } else {
            c = 0.5f;
        }
        out[0] = 1.0f - c;
    }
}

extern "C" void kernel_launch(void* const* d_in, const int* in_sizes, int n_in,
                              void* d_out, int out_size, void* d_ws, size_t ws_size,
                              hipStream_t stream)
{
    const float* risk = (const float*)d_in[0];   // (B,1) f32, flat B
    const float* tim  = (const float*)d_in[1];   // (B,)  f32
    const int*   evt  = (const int*)d_in[2];     // (B,)  i32
    float* out = (float*)d_out;
    uint4* part = (uint4*)d_ws;

    const int n = in_sizes[1];
    const int nt = (n + TILE - 1) / TILE;        // tile rows (128 for n=8192)
    const int ntile = nt * (nt + 1) / 2;         // triangular tile count (8256)
    const int nslot = (ntile + WPB - 1) / WPB;   // blocks / packed slots (2064)

    cindex_pairs_kernel<<<dim3(nslot), 256, 0, stream>>>(risk, tim, evt, part,
                                                         n, ntile);
    cindex_reduce_kernel<<<1, 1024, 0, stream>>>(part, out, nslot);
}